// Round 1
// baseline (4779.290 us; speedup 1.0000x reference)
//
#include <hip/hip_runtime.h>
#include <math.h>

#define CDIV(a,b) (((a)+(b)-1)/(b))

// ---------------- Stockham radix-2 FFT over lines ----------------
// One line of length N handled by N/2 threads; LPB = 256/(N/2) lines per block.
// line L -> base = (L/lpp)*plane_stride + (L%lpp)*line_pitch, elements at base + k*stride.
template<int N, bool REAL_IN>
__global__ __launch_bounds__(256)
void fft_lines(const float* __restrict__ in_real,
               const float2* __restrict__ in_c,
               float2* __restrict__ out_c,
               int nlines, int lpp, int plane_stride, int line_pitch, int stride,
               float sgn, float scale)
{
    constexpr int H = N / 2;
    constexpr int LPB = 256 / H;
    __shared__ float2 bufA[LPB][N];
    __shared__ float2 bufB[LPB][N];
    __shared__ float2 W[H];
    const int tid = threadIdx.x;
    const int sub = tid / H;
    const int b   = tid % H;
    const int L   = blockIdx.x * LPB + sub;

    if (tid < H) {
        float ang = (6.283185307179586f / N) * tid;
        float s, c;
        sincosf(ang, &s, &c);
        W[tid] = make_float2(c, sgn * s);   // e^{sgn*i*2*pi*t/N}; fwd sgn=-1
    }
    const bool active = (L < nlines);
    size_t base = 0;
    if (active) {
        int p = L / lpp, q = L - p * lpp;
        base = (size_t)p * plane_stride + (size_t)q * line_pitch;
        if (REAL_IN) {
            bufA[sub][b]     = make_float2(in_real[base + (size_t)b * stride], 0.f);
            bufA[sub][b + H] = make_float2(in_real[base + (size_t)(b + H) * stride], 0.f);
        } else {
            bufA[sub][b]     = in_c[base + (size_t)b * stride];
            bufA[sub][b + H] = in_c[base + (size_t)(b + H) * stride];
        }
    }
    __syncthreads();
    float2 (*X)[N] = bufA;
    float2 (*Y)[N] = bufB;
    int m = 1;
    #pragma unroll
    for (int l = H; l >= 1; l >>= 1) {
        int jm = b & ~(m - 1);
        float2 c0 = X[sub][b];
        float2 c1 = X[sub][b + H];
        float2 w  = W[jm];
        float2 s0 = make_float2(c0.x + c1.x, c0.y + c1.y);
        float2 d  = make_float2(c0.x - c1.x, c0.y - c1.y);
        float2 t  = make_float2(d.x * w.x - d.y * w.y, d.x * w.y + d.y * w.x);
        Y[sub][b + jm]     = s0;
        Y[sub][b + jm + m] = t;
        __syncthreads();
        float2 (*tmp)[N] = X; X = Y; Y = tmp;
        m <<= 1;
    }
    if (active) {
        float2 r0 = X[sub][b], r1 = X[sub][b + H];
        out_c[base + (size_t)b * stride]       = make_float2(r0.x * scale, r0.y * scale);
        out_c[base + (size_t)(b + H) * stride] = make_float2(r1.x * scale, r1.y * scale);
    }
}

// ---------------- feat abs/angle extraction ----------------
__global__ __launch_bounds__(256)
void extract_feat(const float2* __restrict__ Fc, float* __restrict__ fA,
                  float* __restrict__ fP, int n)
{
    int t = blockIdx.x * 256 + threadIdx.x;
    if (t >= n) return;
    float2 v = Fc[t];
    fA[t] = sqrtf(v.x * v.x + v.y * v.y);
    fP[t] = atan2f(v.y, v.x);
}

// ---------------- build MLP input (both paths; same flat write index) ------
// element t of [65536*258]: n = t/258, c = t%258.
// PHASE=false: featX = |feat_f| plane, guide = |E|   -> inp[n][c]   (row-major)
// PHASE=true : featX = angle(feat_f), guide = angle(E) -> x[ch][p] with
//              ch*65536+p == t  (the torch-faithful .view scramble)
template<bool PHASE>
__global__ __launch_bounds__(256)
void build_inp(const float* __restrict__ featX, const float2* __restrict__ E,
               float* __restrict__ dst, int vx, int vy)
{
    size_t t = (size_t)blockIdx.x * 256 + threadIdx.x;
    if (t >= (size_t)65536 * 258) return;
    int n = (int)(t / 258);
    int c = (int)(t - (size_t)n * 258);
    int i = n >> 8, j = n & 255;
    int iy = (2 * i + (vx < 0 ? -3 : 5)) >> 3;   // exact: round((c_y+1)*32-0.5)
    int ix = (2 * j + (vy < 0 ? -3 : 5)) >> 3;
    bool valid = (iy >= 0 && iy < 64 && ix >= 0 && ix < 64);
    float v;
    if (c < 128) {
        v = valid ? featX[c * 4096 + iy * 64 + ix] : 0.f;
    } else if (c < 256) {
        float2 g = E[(size_t)(c - 128) * 65536 + n];
        v = PHASE ? atan2f(g.y, g.x) : sqrtf(g.x * g.x + g.y * g.y);
    } else if (c == 256) {
        v = valid ? (0.5f * i - 2.f * iy - 0.75f) : (0.5f * i - 63.75f);
    } else {
        v = valid ? (0.5f * j - 2.f * ix - 0.75f) : (0.5f * j - 63.75f);
    }
    dst[t] = v;
}

// ---------------- generic f32 GEMM: C[M,N] = act(A[M,K]@B[K,N] + bias) -----
template<bool RELU, bool HASBIAS>
__global__ __launch_bounds__(256)
void gemm_f32(const float* __restrict__ A, const float* __restrict__ B,
              const float* __restrict__ bias, float* __restrict__ C,
              int M, int N, int K)
{
    __shared__ float As[16][128];
    __shared__ float Bs[16][128];
    const int tid = threadIdx.x;
    const int tx = tid & 15, ty = tid >> 4;
    const int bm = blockIdx.y * 128, bn = blockIdx.x * 128;
    float acc[8][8] = {};
    for (int k0 = 0; k0 < K; k0 += 16) {
        #pragma unroll
        for (int e = 0; e < 8; e++) {
            int flat = tid + e * 256;
            int mm = flat >> 4, kk = flat & 15;
            int gm = bm + mm, gk = k0 + kk;
            As[kk][mm] = (gm < M && gk < K) ? A[(size_t)gm * K + gk] : 0.f;
            int kk2 = flat >> 7, nn = flat & 127;
            int gk2 = k0 + kk2, gn = bn + nn;
            Bs[kk2][nn] = (gk2 < K && gn < N) ? B[(size_t)gk2 * N + gn] : 0.f;
        }
        __syncthreads();
        #pragma unroll
        for (int kk = 0; kk < 16; kk++) {
            float4 a0 = *(const float4*)&As[kk][ty * 8];
            float4 a1 = *(const float4*)&As[kk][ty * 8 + 4];
            float4 b0 = *(const float4*)&Bs[kk][tx * 8];
            float4 b1 = *(const float4*)&Bs[kk][tx * 8 + 4];
            float av[8] = {a0.x, a0.y, a0.z, a0.w, a1.x, a1.y, a1.z, a1.w};
            float bv[8] = {b0.x, b0.y, b0.z, b0.w, b1.x, b1.y, b1.z, b1.w};
            #pragma unroll
            for (int ii = 0; ii < 8; ii++)
                #pragma unroll
                for (int jj = 0; jj < 8; jj++)
                    acc[ii][jj] += av[ii] * bv[jj];
        }
        __syncthreads();
    }
    #pragma unroll
    for (int ii = 0; ii < 8; ii++) {
        int gm = bm + ty * 8 + ii;
        if (gm >= M) continue;
        #pragma unroll
        for (int jj = 0; jj < 8; jj++) {
            int gn = bn + tx * 8 + jj;
            if (gn >= N) continue;
            float v = acc[ii][jj];
            if (HASBIAS) v += bias[gn];
            if (RELU) v = fmaxf(v, 0.f);
            C[(size_t)gm * N + gn] = v;
        }
    }
}

// ---------------- depthwise 3x3, pad 1, zero-pad, per-channel --------------
template<bool RELU>
__global__ __launch_bounds__(256)
void dwconv3(const float* __restrict__ in, const float* __restrict__ w,
             float* __restrict__ out, int C)
{
    int x = blockIdx.x * 16 + (threadIdx.x & 15);
    int y = blockIdx.y * 16 + (threadIdx.x >> 4);
    int cc = blockIdx.z;
    const float* ip = in + (size_t)cc * 65536;
    const float* wp = w + cc * 9;
    float acc = 0.f;
    #pragma unroll
    for (int dy = 0; dy < 3; dy++)
        #pragma unroll
        for (int dx = 0; dx < 3; dx++) {
            int yy = y + dy - 1, xx = x + dx - 1;
            if (yy >= 0 && yy < 256 && xx >= 0 && xx < 256)
                acc += ip[yy * 256 + xx] * wp[dy * 3 + dx];
        }
    if (RELU) acc = fmaxf(acc, 0.f);
    out[(size_t)cc * 65536 + y * 256 + x] = acc;
}

// ---------------- ensemble (mag): preds [4][65536][33] -> mag [32][65536] --
__global__ __launch_bounds__(256)
void ensemble_a(const float* __restrict__ P, float* __restrict__ mag)
{
    int n = blockIdx.x * 256 + threadIdx.x;
    if (n >= 65536) return;
    float w[4]; float mx = -1e30f;
    #pragma unroll
    for (int s = 0; s < 4; s++) {
        w[s] = P[((size_t)s * 65536 + n) * 33 + 32];
        mx = fmaxf(mx, w[s]);
    }
    float sum = 0.f;
    #pragma unroll
    for (int s = 0; s < 4; s++) { w[s] = expf(w[s] - mx); sum += w[s]; }
    float inv = 1.f / sum;
    for (int ch = 0; ch < 32; ch++) {
        float a = 0.f;
        #pragma unroll
        for (int s = 0; s < 4; s++)
            a += P[((size_t)s * 65536 + n) * 33 + ch] * w[s];
        mag[(size_t)ch * 65536 + n] = a * inv;
    }
}

// ------- ensemble (pha): preds [4][33][65536] with view-scramble -> [32][65536]
__global__ __launch_bounds__(256)
void ensemble_p(const float* __restrict__ P, float* __restrict__ pha)
{
    int n = blockIdx.x * 256 + threadIdx.x;
    if (n >= 65536) return;
    size_t fw = (size_t)n * 33 + 32;
    int chw = (int)(fw >> 16), pw = (int)(fw & 65535);
    float w[4]; float mx = -1e30f;
    #pragma unroll
    for (int s = 0; s < 4; s++) {
        w[s] = P[(size_t)s * 2162688 + (size_t)chw * 65536 + pw];
        mx = fmaxf(mx, w[s]);
    }
    float sum = 0.f;
    #pragma unroll
    for (int s = 0; s < 4; s++) { w[s] = expf(w[s] - mx); sum += w[s]; }
    float inv = 1.f / sum;
    for (int jj = 0; jj < 32; jj++) {
        size_t f = (size_t)n * 33 + jj;
        int c2 = (int)(f >> 16), p2 = (int)(f & 65535);
        float a = 0.f;
        #pragma unroll
        for (int s = 0; s < 4; s++)
            a += P[(size_t)s * 2162688 + (size_t)c2 * 65536 + p2] * w[s];
        pha[(size_t)jj * 65536 + n] = a * inv;
    }
}

// ---------------- mag,pha -> complex; and final abs ----------------
__global__ __launch_bounds__(256)
void make_ffted(const float* __restrict__ mag, const float* __restrict__ pha,
                float2* __restrict__ out)
{
    int t = blockIdx.x * 256 + threadIdx.x;
    if (t >= 32 * 65536) return;
    float m = mag[t], p = pha[t];
    float s, c; sincosf(p, &s, &c);
    out[t] = make_float2(m * c, m * s);
}

__global__ __launch_bounds__(256)
void abs_out(const float2* __restrict__ in, float* __restrict__ out, int n)
{
    int t = blockIdx.x * 256 + threadIdx.x;
    if (t >= n) return;
    float2 v = in[t];
    out[t] = sqrtf(v.x * v.x + v.y * v.y);
}

extern "C" void kernel_launch(void* const* d_in, const int* in_sizes, int n_in,
                              void* d_out, int out_size, void* d_ws, size_t ws_size,
                              hipStream_t stream)
{
    (void)in_sizes; (void)n_in; (void)out_size; (void)ws_size;
    const float* feat = (const float*)d_in[0];
    const float* hr   = (const float*)d_in[2];
    const float* w1a  = (const float*)d_in[3];
    const float* b1a  = (const float*)d_in[4];
    const float* w2a  = (const float*)d_in[5];
    const float* b2a  = (const float*)d_in[6];
    const float* w3a  = (const float*)d_in[7];
    const float* b3a  = (const float*)d_in[8];
    const float* pw1  = (const float*)d_in[9];
    const float* dw1  = (const float*)d_in[10];
    const float* pw2  = (const float*)d_in[11];
    const float* dw2  = (const float*)d_in[12];
    const float* pw3  = (const float*)d_in[13];
    const float* dw3  = (const float*)d_in[14];

    float* ws = (float*)d_ws;
    float2* E    = (float2*)ws;            // guide complex: 128*65536 c = 16,777,216 f
    float* featA = ws + 16777216;          // 524,288 f
    float* featP = featA + 524288;         // 524,288 f
    float* F     = featP + 524288;         // 16,908,288 f  (inp / h-buffers)
    float* F2    = F + 16908288;           // 16,777,216 f
    float* G     = F2 + 16777216;          // 8,650,752 f   (preds, both paths)
    float* Hm    = G + 8650752;            // 2,097,152 f   (mag [32][65536])
    float* Hp    = Hm + 2097152;           // 2,097,152 f   (pha [32][65536])
    float2* Fc   = (float2*)F;             // feat complex (temp, 1,048,576 f)

    // ---- forward FFTs (rows then cols, in-place for col pass) ----
    fft_lines<256, true ><<<16384, 256, 0, stream>>>(hr, nullptr, E, 32768, 256, 65536, 256, 1, -1.f, 1.f);
    fft_lines<256, false><<<16384, 256, 0, stream>>>(nullptr, E, E, 32768, 256, 65536, 1, 256, -1.f, 1.f);
    fft_lines<64,  true ><<<1024,  256, 0, stream>>>(feat, nullptr, Fc, 8192, 64, 4096, 64, 1, -1.f, 1.f);
    fft_lines<64,  false><<<1024,  256, 0, stream>>>(nullptr, Fc, Fc, 8192, 64, 4096, 1, 64, -1.f, 1.f);
    extract_feat<<<2048, 256, 0, stream>>>(Fc, featA, featP, 524288);

    const int nb_inp = (int)CDIV((size_t)65536 * 258, 256);

    // ---- magnitude path: plain MLP 258->256->128->33, 4 shifts ----
    for (int s = 0; s < 4; s++) {
        int vx = (s < 2) ? -1 : 1;
        int vy = (s & 1) ? 1 : -1;
        build_inp<false><<<nb_inp, 256, 0, stream>>>(featA, E, F, vx, vy);
        gemm_f32<true,  true ><<<dim3(2, 512), 256, 0, stream>>>(F,  w1a, b1a, F2, 65536, 256, 258);
        gemm_f32<true,  true ><<<dim3(1, 512), 256, 0, stream>>>(F2, w2a, b2a, F,  65536, 128, 256);
        gemm_f32<false, true ><<<dim3(1, 512), 256, 0, stream>>>(F,  w3a, b3a, G + (size_t)s * 65536 * 33, 65536, 33, 128);
    }
    ensemble_a<<<256, 256, 0, stream>>>(G, Hm);

    // ---- phase path: scrambled conv MLP (pw+dw)x3, 4 shifts ----
    for (int s = 0; s < 4; s++) {
        int vx = (s < 2) ? -1 : 1;
        int vy = (s & 1) ? 1 : -1;
        build_inp<true><<<nb_inp, 256, 0, stream>>>(featP, E, F, vx, vy);
        gemm_f32<false, false><<<dim3(512, 2), 256, 0, stream>>>(pw1, F, nullptr, F2, 256, 65536, 258);
        dwconv3<true ><<<dim3(16, 16, 256), 256, 0, stream>>>(F2, dw1, F, 256);
        gemm_f32<false, false><<<dim3(512, 1), 256, 0, stream>>>(pw2, F, nullptr, F2, 128, 65536, 256);
        dwconv3<true ><<<dim3(16, 16, 128), 256, 0, stream>>>(F2, dw2, F, 128);
        gemm_f32<false, false><<<dim3(512, 1), 256, 0, stream>>>(pw3, F, nullptr, F2, 33, 65536, 128);
        dwconv3<false><<<dim3(16, 16, 33), 256, 0, stream>>>(F2, dw3, G + (size_t)s * 2162688, 33);
    }
    ensemble_p<<<256, 256, 0, stream>>>(G, Hp);

    // ---- recombine + inverse FFT + abs ----
    make_ffted<<<8192, 256, 0, stream>>>(Hm, Hp, E);
    fft_lines<256, false><<<4096, 256, 0, stream>>>(nullptr, E, E, 8192, 256, 65536, 256, 1, 1.f, 1.f / 256.f);
    fft_lines<256, false><<<4096, 256, 0, stream>>>(nullptr, E, E, 8192, 256, 65536, 1, 256, 1.f, 1.f / 256.f);
    abs_out<<<8192, 256, 0, stream>>>(E, (float*)d_out, 2097152);
}

// Round 3
// 2107.982 us; speedup vs baseline: 2.2672x; 2.2672x over previous
//
#include <hip/hip_runtime.h>
#include <math.h>

typedef __attribute__((ext_vector_type(4))) float f32x4;
typedef __attribute__((ext_vector_type(8))) short bf16x8;

__device__ __forceinline__ short f2bf(float v) {
    union { float f; unsigned u; } x; x.f = v;
    unsigned r = x.u + 0x7FFF + ((x.u >> 16) & 1);
    return (short)(r >> 16);
}
__device__ __forceinline__ float bf2f(short b) {
    union { unsigned u; float f; } x; x.u = ((unsigned)(unsigned short)b) << 16;
    return x.f;
}
__device__ __forceinline__ void gload16(const void* g, void* l) {
    __builtin_amdgcn_global_load_lds((const __attribute__((address_space(1))) void*)g,
                                     (__attribute__((address_space(3))) void*)l, 16, 0, 0);
}

// ---------------- Stockham radix-2 FFT over lines (verified round 1) -------
template<int N, bool REAL_IN>
__global__ __launch_bounds__(256)
void fft_lines(const float* __restrict__ in_real,
               const float2* __restrict__ in_c,
               float2* __restrict__ out_c,
               int nlines, int lpp, int plane_stride, int line_pitch, int stride,
               float sgn, float scale)
{
    constexpr int H = N / 2;
    constexpr int LPB = 256 / H;
    __shared__ float2 bufA[LPB][N];
    __shared__ float2 bufB[LPB][N];
    __shared__ float2 W[H];
    const int tid = threadIdx.x;
    const int sub = tid / H;
    const int b   = tid % H;
    const int L   = blockIdx.x * LPB + sub;
    if (tid < H) {
        float ang = (6.283185307179586f / N) * tid;
        float s, c; sincosf(ang, &s, &c);
        W[tid] = make_float2(c, sgn * s);
    }
    const bool active = (L < nlines);
    size_t base = 0;
    if (active) {
        int p = L / lpp, q = L - p * lpp;
        base = (size_t)p * plane_stride + (size_t)q * line_pitch;
        if (REAL_IN) {
            bufA[sub][b]     = make_float2(in_real[base + (size_t)b * stride], 0.f);
            bufA[sub][b + H] = make_float2(in_real[base + (size_t)(b + H) * stride], 0.f);
        } else {
            bufA[sub][b]     = in_c[base + (size_t)b * stride];
            bufA[sub][b + H] = in_c[base + (size_t)(b + H) * stride];
        }
    }
    __syncthreads();
    float2 (*X)[N] = bufA;
    float2 (*Y)[N] = bufB;
    int m = 1;
    #pragma unroll
    for (int l = H; l >= 1; l >>= 1) {
        int jm = b & ~(m - 1);
        float2 c0 = X[sub][b];
        float2 c1 = X[sub][b + H];
        float2 w  = W[jm];
        float2 s0 = make_float2(c0.x + c1.x, c0.y + c1.y);
        float2 d  = make_float2(c0.x - c1.x, c0.y - c1.y);
        float2 t  = make_float2(d.x * w.x - d.y * w.y, d.x * w.y + d.y * w.x);
        Y[sub][b + jm]     = s0;
        Y[sub][b + jm + m] = t;
        __syncthreads();
        float2 (*tmp)[N] = X; X = Y; Y = tmp;
        m <<= 1;
    }
    if (active) {
        float2 r0 = X[sub][b], r1 = X[sub][b + H];
        out_c[base + (size_t)b * stride]       = make_float2(r0.x * scale, r0.y * scale);
        out_c[base + (size_t)(b + H) * stride] = make_float2(r1.x * scale, r1.y * scale);
    }
}

__global__ __launch_bounds__(256)
void extract_feat(const float2* __restrict__ Fc, float* __restrict__ fA,
                  float* __restrict__ fP, int n)
{
    int t = blockIdx.x * 256 + threadIdx.x;
    if (t >= n) return;
    float2 v = Fc[t];
    fA[t] = sqrtf(v.x * v.x + v.y * v.y);
    fP[t] = atan2f(v.y, v.x);
}

// guide builders: Ga bf16 [65536][128] (mags); Gpf f32 [65536][128] (angles)
__global__ __launch_bounds__(256)
void gbuild(const float2* __restrict__ E, short* __restrict__ Ga, float* __restrict__ Gpf)
{
    int n0 = blockIdx.x * 32;
    #pragma unroll 4
    for (int e = 0; e < 16; e++) {
        int idx = threadIdx.x + e * 256;
        int n = n0 + (idx >> 7), c = idx & 127;
        float2 v = E[(size_t)c * 65536 + n];
        Ga[(size_t)n * 128 + c]  = f2bf(sqrtf(v.x * v.x + v.y * v.y));
        Gpf[(size_t)n * 128 + c] = atan2f(v.y, v.x);
    }
}

// mag-path per-shift feat rows: Af bf16 [65536][160] (128 feat + 2 rel + pad)
__global__ __launch_bounds__(256)
void bfeat_a(const float* __restrict__ featA, short* __restrict__ Af, int vx, int vy)
{
    int t = blockIdx.x * 256 + threadIdx.x;
    int n = t / 160, j = t - n * 160;
    int i = n >> 8, jx = n & 255;
    int iy = (2 * i + (vx < 0 ? -3 : 5)) >> 3;
    int ix = (2 * jx + (vy < 0 ? -3 : 5)) >> 3;
    bool valid = (iy >= 0 && iy < 64 && ix >= 0 && ix < 64);
    float v = 0.f;
    if (j < 128)       v = valid ? featA[j * 4096 + iy * 64 + ix] : 0.f;
    else if (j == 128) v = valid ? (0.5f * i - 2.f * iy - 0.75f) : (0.5f * i - 63.75f);
    else if (j == 129) v = valid ? (0.5f * jx - 2.f * ix - 0.75f) : (0.5f * jx - 63.75f);
    Af[(size_t)n * 160 + j] = f2bf(v);
}

// phase-path per-shift SCRAMBLED input: Xp hi/lo [65536][576], hi ch j<258.
// x[ch][p] = inp[(ch*65536+p)/258][(ch*65536+p)%258]  (torch .view faithful)
__global__ __launch_bounds__(256)
void bphase(const float* __restrict__ featP, const float* __restrict__ Gpf,
            short* __restrict__ Xp, int vx, int vy)
{
    unsigned t = blockIdx.x * 256 + threadIdx.x;
    if (t >= 65536u * 288u) return;
    unsigned p = t / 288u, j = t - p * 288u;
    float v = 0.f;
    if (j < 258u) {
        unsigned f = j * 65536u + p;
        unsigned n = f / 258u;
        unsigned c = f - n * 258u;
        int i = (int)(n >> 8), jx = (int)(n & 255);
        int iy = (2 * i + (vx < 0 ? -3 : 5)) >> 3;
        int ix = (2 * jx + (vy < 0 ? -3 : 5)) >> 3;
        bool valid = (iy >= 0 && iy < 64 && ix >= 0 && ix < 64);
        if (c < 128u)       v = valid ? featP[c * 4096 + iy * 64 + ix] : 0.f;
        else if (c < 256u)  v = Gpf[(size_t)n * 128 + (c - 128)];
        else if (c == 256u) v = valid ? (0.5f * i - 2.f * iy - 0.75f) : (0.5f * i - 63.75f);
        else                v = valid ? (0.5f * jx - 2.f * ix - 0.75f) : (0.5f * jx - 63.75f);
    }
    short hi = f2bf(v);
    Xp[(size_t)p * 576 + j]       = hi;
    Xp[(size_t)p * 576 + 288 + j] = f2bf(v - bf2f(hi));
}

// ---------------- weight prep ----------------
// dst[o][j] bf16 [Nd][Kp]; src f32 [Ktot][Ncols] read transposed; col map.
__global__ void wprep_T(const float* __restrict__ src, short* __restrict__ dst,
                        int Ncols, int Nd, int Kp, int k0, int kn, int kr0, int krn)
{
    int t = blockIdx.x * 256 + threadIdx.x;
    if (t >= Nd * Kp) return;
    int o = t / Kp, j = t - o * Kp;
    int c = (j < kn) ? (k0 + j) : ((j < kn + krn) ? (kr0 + j - kn) : -1);
    float v = 0.f;
    if (c >= 0 && o < Ncols) v = src[(size_t)c * Ncols + o];
    dst[t] = f2bf(v);
}
// src f32 [Nsrc][Ksrc] row-major; dst bf16 [Nd][2*Kh] hi|lo.
__global__ void wprep_hilo(const float* __restrict__ src, short* __restrict__ dst,
                           int Nsrc, int Ksrc, int Nd, int Kh, int kn)
{
    int t = blockIdx.x * 256 + threadIdx.x;
    if (t >= Nd * Kh) return;
    int o = t / Kh, j = t - o * Kh;
    float v = 0.f;
    if (j < kn && o < Nsrc) v = src[(size_t)o * Ksrc + j];
    short hi = f2bf(v);
    dst[(size_t)o * (2 * Kh) + j]      = hi;
    dst[(size_t)o * (2 * Kh) + Kh + j] = f2bf(v - bf2f(hi));
}

// ---------------- MFMA GEMM: C[M,*] = act(A[M,K] @ Bt[N,K]^T (+bias)(+Cin))
template<int HILO, int RELU, int BIAS, int CIN, int OUTF32>
__global__ __launch_bounds__(256)
void gemm_mfma(const short* __restrict__ A, const short* __restrict__ Bt,
               const float* __restrict__ bias, const void* __restrict__ Cin,
               void* __restrict__ Cout,
               int K, int Apitch, int Bpitch, int ldc, int Nout)
{
    constexpr int NB = HILO ? 2 : 1;
    __shared__ short As[NB * 4096];
    __shared__ short Bs[NB * 4096];
    const int tid = threadIdx.x;
    const int wave = tid >> 6, lane = tid & 63;
    const int bm = blockIdx.y * 128, bn = blockIdx.x * 128;
    const int wr = wave >> 1, wc = wave & 1;
    const int srow = wave * 32 + (lane >> 2);
    const int scol = (lane & 3) * 8;
    const int ldsoff = srow * 32 + scol;
    f32x4 acc[4][4] = {};
    const int ks_n = K >> 5;
    for (int ks = 0; ks < ks_n; ks++) {
        const int k0 = ks << 5;
        const short* gA = A + (size_t)(bm + srow) * Apitch + k0 + scol;
        gload16(gA, &As[ldsoff]);
        gload16(gA + 16 * Apitch, &As[ldsoff + 512]);
        const short* gB = Bt + (size_t)(bn + srow) * Bpitch + k0 + scol;
        gload16(gB, &Bs[ldsoff]);
        gload16(gB + 16 * Bpitch, &Bs[ldsoff + 512]);
        if constexpr (HILO) {
            const short* gAl = gA + K;
            gload16(gAl, &As[4096 + ldsoff]);
            gload16(gAl + 16 * Apitch, &As[4096 + ldsoff + 512]);
            const short* gBl = gB + K;
            gload16(gBl, &Bs[4096 + ldsoff]);
            gload16(gBl + 16 * Bpitch, &Bs[4096 + ldsoff + 512]);
        }
        __syncthreads();
        const int fr = lane & 15;
        const int kreg = (lane >> 4) << 3;
        bf16x8 ah[4], bh[4];
        #pragma unroll
        for (int m = 0; m < 4; m++)
            ah[m] = *(const bf16x8*)&As[(wr * 64 + m * 16 + fr) * 32 + kreg];
        #pragma unroll
        for (int n = 0; n < 4; n++)
            bh[n] = *(const bf16x8*)&Bs[(wc * 64 + n * 16 + fr) * 32 + kreg];
        if constexpr (HILO) {
            bf16x8 al[4], bl[4];
            #pragma unroll
            for (int m = 0; m < 4; m++)
                al[m] = *(const bf16x8*)&As[4096 + (wr * 64 + m * 16 + fr) * 32 + kreg];
            #pragma unroll
            for (int n = 0; n < 4; n++)
                bl[n] = *(const bf16x8*)&Bs[4096 + (wc * 64 + n * 16 + fr) * 32 + kreg];
            #pragma unroll
            for (int m = 0; m < 4; m++)
                #pragma unroll
                for (int n = 0; n < 4; n++) {
                    acc[m][n] = __builtin_amdgcn_mfma_f32_16x16x32_bf16(ah[m], bh[n], acc[m][n], 0, 0, 0);
                    acc[m][n] = __builtin_amdgcn_mfma_f32_16x16x32_bf16(al[m], bh[n], acc[m][n], 0, 0, 0);
                    acc[m][n] = __builtin_amdgcn_mfma_f32_16x16x32_bf16(ah[m], bl[n], acc[m][n], 0, 0, 0);
                }
        } else {
            #pragma unroll
            for (int m = 0; m < 4; m++)
                #pragma unroll
                for (int n = 0; n < 4; n++)
                    acc[m][n] = __builtin_amdgcn_mfma_f32_16x16x32_bf16(ah[m], bh[n], acc[m][n], 0, 0, 0);
        }
        __syncthreads();
    }
    const int fr = lane & 15;
    const int rg = (lane >> 4) * 4;
    #pragma unroll
    for (int n = 0; n < 4; n++) {
        const int col = bn + wc * 64 + n * 16 + fr;
        if (col >= Nout) continue;
        const float bv = BIAS ? bias[col] : 0.f;
        #pragma unroll
        for (int m = 0; m < 4; m++) {
            const int row0 = bm + wr * 64 + m * 16 + rg;
            #pragma unroll
            for (int r = 0; r < 4; r++) {
                float v = acc[m][n][r] + bv;
                const size_t ci = (size_t)(row0 + r) * ldc + col;
                if (CIN == 1) v += bf2f(((const short*)Cin)[ci]);
                if (RELU) v = fmaxf(v, 0.f);
                if (OUTF32) ((float*)Cout)[ci] = v;
                else        ((short*)Cout)[ci] = f2bf(v);
            }
        }
    }
}

// depthwise 3x3, channel-last [65536][C] f32 in -> bf16 hi/lo out [65536][2C]
template<int C, int RELU>
__global__ __launch_bounds__(256)
void dwconv_hilo(const float* __restrict__ in, const float* __restrict__ w,
                 short* __restrict__ out)
{
    constexpr int PPB = 256 / C;
    const int tid = threadIdx.x;
    const int c = tid % C, pl = tid / C;
    const int p = blockIdx.x * PPB + pl;
    const int y = p >> 8, x = p & 255;
    float wk[9];
    #pragma unroll
    for (int k = 0; k < 9; k++) wk[k] = w[c * 9 + k];
    float acc = 0.f;
    #pragma unroll
    for (int dy = 0; dy < 3; dy++) {
        int yy = y + dy - 1;
        if (yy < 0 || yy > 255) continue;
        #pragma unroll
        for (int dx = 0; dx < 3; dx++) {
            int xx = x + dx - 1;
            if (xx < 0 || xx > 255) continue;
            acc += in[(size_t)(yy * 256 + xx) * C + c] * wk[dy * 3 + dx];
        }
    }
    if (RELU) acc = fmaxf(acc, 0.f);
    short hi = f2bf(acc);
    out[(size_t)p * (2 * C) + c]     = hi;
    out[(size_t)p * (2 * C) + C + c] = f2bf(acc - bf2f(hi));
}

// dw3: in C3 f32 [65536][33], w [33][9], out f32 [65536][33]
__global__ __launch_bounds__(256)
void dwconv3_f32(const float* __restrict__ in, const float* __restrict__ w,
                 float* __restrict__ out)
{
    const int tid = threadIdx.x;
    const int c = tid & 63, pl = tid >> 6;
    if (c >= 33) return;
    const int p = blockIdx.x * 4 + pl;
    const int y = p >> 8, x = p & 255;
    float wk[9];
    #pragma unroll
    for (int k = 0; k < 9; k++) wk[k] = w[c * 9 + k];
    float acc = 0.f;
    #pragma unroll
    for (int dy = 0; dy < 3; dy++) {
        int yy = y + dy - 1;
        if (yy < 0 || yy > 255) continue;
        #pragma unroll
        for (int dx = 0; dx < 3; dx++) {
            int xx = x + dx - 1;
            if (xx < 0 || xx > 255) continue;
            acc += in[(size_t)(yy * 256 + xx) * 33 + c] * wk[dy * 3 + dx];
        }
    }
    out[(size_t)p * 33 + c] = acc;
}

// ---------------- ensembles ----------------
__global__ __launch_bounds__(256)
void ensemble_a(const short* __restrict__ P, float* __restrict__ mag)
{
    int n = blockIdx.x * 256 + threadIdx.x;
    float w[4]; float mx = -1e30f;
    #pragma unroll
    for (int s = 0; s < 4; s++) {
        w[s] = bf2f(P[((size_t)s * 65536 + n) * 33 + 32]);
        mx = fmaxf(mx, w[s]);
    }
    float sum = 0.f;
    #pragma unroll
    for (int s = 0; s < 4; s++) { w[s] = expf(w[s] - mx); sum += w[s]; }
    float inv = 1.f / sum;
    for (int ch = 0; ch < 32; ch++) {
        float a = 0.f;
        #pragma unroll
        for (int s = 0; s < 4; s++)
            a += bf2f(P[((size_t)s * 65536 + n) * 33 + ch]) * w[s];
        mag[(size_t)ch * 65536 + n] = a * inv;
    }
}

// preds stored channel-last [65536][33] per shift; output view scramble:
// preds(n,jj) = conv[ch=(n*33+jj)>>16][p=(n*33+jj)&65535] = P[p*33+ch]
__global__ __launch_bounds__(256)
void ensemble_p(const float* __restrict__ P, float* __restrict__ pha)
{
    const size_t SOFF = (size_t)65536 * 33;
    int n = blockIdx.x * 256 + threadIdx.x;
    size_t fw = (size_t)n * 33 + 32;
    int cw = (int)(fw >> 16), pw_ = (int)(fw & 65535);
    float w[4]; float mx = -1e30f;
    #pragma unroll
    for (int s = 0; s < 4; s++) {
        w[s] = P[(size_t)s * SOFF + (size_t)pw_ * 33 + cw];
        mx = fmaxf(mx, w[s]);
    }
    float sum = 0.f;
    #pragma unroll
    for (int s = 0; s < 4; s++) { w[s] = expf(w[s] - mx); sum += w[s]; }
    float inv = 1.f / sum;
    for (int jj = 0; jj < 32; jj++) {
        size_t f = (size_t)n * 33 + jj;
        int c2 = (int)(f >> 16), p2 = (int)(f & 65535);
        float a = 0.f;
        #pragma unroll
        for (int s = 0; s < 4; s++)
            a += P[(size_t)s * SOFF + (size_t)p2 * 33 + c2] * w[s];
        pha[(size_t)jj * 65536 + n] = a * inv;
    }
}

__global__ __launch_bounds__(256)
void make_ffted(const float* __restrict__ mag, const float* __restrict__ pha,
                float2* __restrict__ out)
{
    int t = blockIdx.x * 256 + threadIdx.x;
    float m = mag[t], p = pha[t];
    float s, c; sincosf(p, &s, &c);
    out[t] = make_float2(m * c, m * s);
}

__global__ __launch_bounds__(256)
void abs_out(const float2* __restrict__ in, float* __restrict__ out)
{
    int t = blockIdx.x * 256 + threadIdx.x;
    float2 v = in[t];
    out[t] = sqrtf(v.x * v.x + v.y * v.y);
}

extern "C" void kernel_launch(void* const* d_in, const int* in_sizes, int n_in,
                              void* d_out, int out_size, void* d_ws, size_t ws_size,
                              hipStream_t stream)
{
    (void)in_sizes; (void)n_in; (void)out_size; (void)ws_size;
    const float* feat = (const float*)d_in[0];
    const float* hr   = (const float*)d_in[2];
    const float* w1a  = (const float*)d_in[3];
    const float* b1a  = (const float*)d_in[4];
    const float* w2a  = (const float*)d_in[5];
    const float* b2a  = (const float*)d_in[6];
    const float* w3a  = (const float*)d_in[7];
    const float* b3a  = (const float*)d_in[8];
    const float* pw1  = (const float*)d_in[9];
    const float* dw1  = (const float*)d_in[10];
    const float* pw2  = (const float*)d_in[11];
    const float* dw2  = (const float*)d_in[12];
    const float* pw3  = (const float*)d_in[13];
    const float* dw3  = (const float*)d_in[14];

    // Workspace plan: 224,133,120 B total (< 257.4 MB proven in round 1).
    char* W = (char*)d_ws;
    const size_t oA = 0;                   // 75,497,472: E / Xp / X2 / Af+h1 / C3 / Hp
    const size_t oB = 75497472;            // 67,108,864: Fc / Ga+H1g+h2 / C1 / C2+X3 / Z
    const size_t oC = oB + 67108864;       // 33,554,432: Gpf f32 [65536][128]
    const size_t oD = oC + 33554432;       // 34,603,008: PA bf16 / PP f32 [4][65536][33]
    const size_t oM = oD + 34603008;       // 12,582,912: featA, featP, Hm
    const size_t oF = oM + 12582912;       //    786,432: weights

    float2* E    = (float2*)(W + oA);
    short*  Xp   = (short*) (W + oA);
    short*  X2   = (short*) (W + oA);
    short*  Af   = (short*) (W + oA);
    short*  h1   = (short*) (W + oA + 20971520);
    float*  C3   = (float*) (W + oA);
    float*  Hp   = (float*) (W + oA);
    float2* Fc   = (float2*)(W + oB);
    short*  Ga   = (short*) (W + oB);
    short*  H1g  = (short*) (W + oB + 16777216);
    short*  h2   = (short*) (W + oB + 50331648);
    float*  C1   = (float*) (W + oB);
    float*  C2   = (float*) (W + oB);
    short*  X3   = (short*) (W + oB + 33554432);
    float2* Z    = (float2*)(W + oB);
    float*  Gpf  = (float*) (W + oC);
    short*  PA   = (short*) (W + oD);
    float*  PP   = (float*) (W + oD);
    float*  featA = (float*)(W + oM);
    float*  featP = (float*)(W + oM + 2097152);
    float*  Hm    = (float*)(W + oM + 4194304);
    short* W1f = (short*)(W + oF);             //  81,920 B [256][160]
    short* W1g = (short*)(W + oF + 81920);     //  65,536 B [256][128]
    short* W2  = (short*)(W + oF + 147456);    //  65,536 B [128][256]
    short* W3  = (short*)(W + oF + 212992);    //  32,768 B [128][128]
    short* Pf  = (short*)(W + oF + 245760);    // 294,912 B [256][576]
    short* P2  = (short*)(W + oF + 540672);    // 131,072 B [128][512]
    short* P3  = (short*)(W + oF + 671744);    //  65,536 B [128][256]

    // ---- weight prep ----
    wprep_T<<<160, 256, 0, stream>>>(w1a, W1f, 256, 256, 160, 0, 128, 256, 2);
    wprep_T<<<128, 256, 0, stream>>>(w1a, W1g, 256, 256, 128, 128, 128, 0, 0);
    wprep_T<<<128, 256, 0, stream>>>(w2a, W2, 128, 128, 256, 0, 256, 0, 0);
    wprep_T<<<64,  256, 0, stream>>>(w3a, W3, 33, 128, 128, 0, 128, 0, 0);
    wprep_hilo<<<288, 256, 0, stream>>>(pw1, Pf, 256, 258, 256, 288, 258);
    wprep_hilo<<<128, 256, 0, stream>>>(pw2, P2, 128, 256, 128, 256, 256);
    wprep_hilo<<<64,  256, 0, stream>>>(pw3, P3, 33, 128, 128, 128, 128);

    // ---- forward FFTs ----
    fft_lines<256, true ><<<16384, 256, 0, stream>>>(hr, nullptr, E, 32768, 256, 65536, 256, 1, -1.f, 1.f);
    fft_lines<256, false><<<16384, 256, 0, stream>>>(nullptr, E, E, 32768, 256, 65536, 1, 256, -1.f, 1.f);
    fft_lines<64,  true ><<<1024,  256, 0, stream>>>(feat, nullptr, Fc, 8192, 64, 4096, 64, 1, -1.f, 1.f);
    fft_lines<64,  false><<<1024,  256, 0, stream>>>(nullptr, Fc, Fc, 8192, 64, 4096, 1, 64, -1.f, 1.f);
    extract_feat<<<2048, 256, 0, stream>>>(Fc, featA, featP, 524288);

    // ---- guide mags/angles (E dead after) ----
    gbuild<<<2048, 256, 0, stream>>>(E, Ga, Gpf);

    // ---- mag-path guide contribution (shift-independent; valid: no scramble)
    gemm_mfma<0,0,0,0,0><<<dim3(2,512), 256, 0, stream>>>(Ga, W1g, nullptr, nullptr, H1g, 128, 128, 128, 256, 256);

    // ---- magnitude path ----
    for (int s = 0; s < 4; s++) {
        int vx = (s < 2) ? -1 : 1;
        int vy = (s & 1) ? 1 : -1;
        bfeat_a<<<40960, 256, 0, stream>>>(featA, Af, vx, vy);
        gemm_mfma<0,1,1,1,0><<<dim3(2,512), 256, 0, stream>>>(Af, W1f, b1a, H1g, h1, 160, 160, 160, 256, 256);
        gemm_mfma<0,1,1,0,0><<<dim3(1,512), 256, 0, stream>>>(h1, W2, b2a, nullptr, h2, 256, 256, 256, 128, 128);
        gemm_mfma<0,0,1,0,0><<<dim3(1,512), 256, 0, stream>>>(h2, W3, b3a, nullptr, PA + (size_t)s * 65536 * 33, 128, 128, 128, 33, 33);
    }
    ensemble_a<<<256, 256, 0, stream>>>(PA, Hm);

    // ---- phase path: scrambled input, hi/lo f32-accurate GEMMs ----
    for (int s = 0; s < 4; s++) {
        int vx = (s < 2) ? -1 : 1;
        int vy = (s & 1) ? 1 : -1;
        bphase<<<73728, 256, 0, stream>>>(featP, Gpf, Xp, vx, vy);
        gemm_mfma<1,0,0,0,1><<<dim3(2,512), 256, 0, stream>>>(Xp, Pf, nullptr, nullptr, C1, 288, 576, 576, 256, 256);
        dwconv_hilo<256,1><<<65536, 256, 0, stream>>>(C1, dw1, X2);
        gemm_mfma<1,0,0,0,1><<<dim3(1,512), 256, 0, stream>>>(X2, P2, nullptr, nullptr, C2, 256, 512, 512, 128, 128);
        dwconv_hilo<128,1><<<32768, 256, 0, stream>>>(C2, dw2, X3);
        gemm_mfma<1,0,0,0,1><<<dim3(1,512), 256, 0, stream>>>(X3, P3, nullptr, nullptr, C3, 128, 256, 256, 33, 33);
        dwconv3_f32<<<16384, 256, 0, stream>>>(C3, dw3, PP + (size_t)s * 65536 * 33);
    }
    ensemble_p<<<256, 256, 0, stream>>>(PP, Hp);

    // ---- recombine + inverse FFT + abs ----
    make_ffted<<<8192, 256, 0, stream>>>(Hm, Hp, Z);
    fft_lines<256, false><<<4096, 256, 0, stream>>>(nullptr, Z, Z, 8192, 256, 65536, 256, 1, 1.f, 1.f / 256.f);
    fft_lines<256, false><<<4096, 256, 0, stream>>>(nullptr, Z, Z, 8192, 256, 65536, 1, 256, 1.f, 1.f / 256.f);
    abs_out<<<8192, 256, 0, stream>>>(Z, (float*)d_out);
}

// Round 4
// 1976.899 us; speedup vs baseline: 2.4176x; 1.0663x over previous
//
#include <hip/hip_runtime.h>
#include <math.h>

typedef __attribute__((ext_vector_type(4))) float f32x4;
typedef __attribute__((ext_vector_type(8))) short bf16x8;

__device__ __forceinline__ short f2bf(float v) {
    union { float f; unsigned u; } x; x.f = v;
    unsigned r = x.u + 0x7FFF + ((x.u >> 16) & 1);
    return (short)(r >> 16);
}
__device__ __forceinline__ float bf2f(short b) {
    union { unsigned u; float f; } x; x.u = ((unsigned)(unsigned short)b) << 16;
    return x.f;
}
__device__ __forceinline__ void gload16(const void* g, void* l) {
    __builtin_amdgcn_global_load_lds((const __attribute__((address_space(1))) void*)g,
                                     (__attribute__((address_space(3))) void*)l, 16, 0, 0);
}

// ---------------- Stockham radix-2 FFT over ROWS (coalesced; verified) -----
template<int N, bool REAL_IN>
__global__ __launch_bounds__(256)
void fft_lines(const float* __restrict__ in_real,
               const float2* __restrict__ in_c,
               float2* __restrict__ out_c,
               int nlines, int lpp, int plane_stride, int line_pitch, int stride,
               float sgn, float scale)
{
    constexpr int H = N / 2;
    constexpr int LPB = 256 / H;
    __shared__ float2 bufA[LPB][N];
    __shared__ float2 bufB[LPB][N];
    __shared__ float2 W[H];
    const int tid = threadIdx.x;
    const int sub = tid / H;
    const int b   = tid % H;
    const int L   = blockIdx.x * LPB + sub;
    if (tid < H) {
        float ang = (6.283185307179586f / N) * tid;
        float s, c; sincosf(ang, &s, &c);
        W[tid] = make_float2(c, sgn * s);
    }
    const bool active = (L < nlines);
    size_t base = 0;
    if (active) {
        int p = L / lpp, q = L - p * lpp;
        base = (size_t)p * plane_stride + (size_t)q * line_pitch;
        if (REAL_IN) {
            bufA[sub][b]     = make_float2(in_real[base + (size_t)b * stride], 0.f);
            bufA[sub][b + H] = make_float2(in_real[base + (size_t)(b + H) * stride], 0.f);
        } else {
            bufA[sub][b]     = in_c[base + (size_t)b * stride];
            bufA[sub][b + H] = in_c[base + (size_t)(b + H) * stride];
        }
    }
    __syncthreads();
    float2 (*X)[N] = bufA;
    float2 (*Y)[N] = bufB;
    int m = 1;
    #pragma unroll
    for (int l = H; l >= 1; l >>= 1) {
        int jm = b & ~(m - 1);
        float2 c0 = X[sub][b];
        float2 c1 = X[sub][b + H];
        float2 w  = W[jm];
        float2 s0 = make_float2(c0.x + c1.x, c0.y + c1.y);
        float2 d  = make_float2(c0.x - c1.x, c0.y - c1.y);
        float2 t  = make_float2(d.x * w.x - d.y * w.y, d.x * w.y + d.y * w.x);
        Y[sub][b + jm]     = s0;
        Y[sub][b + jm + m] = t;
        __syncthreads();
        float2 (*tmp)[N] = X; X = Y; Y = tmp;
        m <<= 1;
    }
    if (active) {
        float2 r0 = X[sub][b], r1 = X[sub][b + H];
        out_c[base + (size_t)b * stride]       = make_float2(r0.x * scale, r0.y * scale);
        out_c[base + (size_t)(b + H) * stride] = make_float2(r1.x * scale, r1.y * scale);
    }
}

// ---------------- tiled COLUMN FFT: coalesced via LDS tile -----------------
// plane = blockIdx.y, col-tile c0 = blockIdx.x*TC. In-place safe (per-tile).
// ABSOUT: write scale*|z| to out_real instead of complex.
template<int N, int TC, int ABSOUT>
__global__ __launch_bounds__(256)
void fft_cols(const float2* __restrict__ in, float2* __restrict__ outc,
              float* __restrict__ outr, float sgn, float scale)
{
    constexpr int H   = N / 2;
    constexpr int ELD = (N * TC) / 256;        // load/store iters
    constexpr int EBF = (H * TC) / 256;        // butterfly iters per stage
    __shared__ float2 bufA[N][TC + 1];
    __shared__ float2 bufB[N][TC + 1];
    __shared__ float2 W[H];
    const int tid = threadIdx.x;
    const int plane = blockIdx.y;
    const int c0 = blockIdx.x * TC;
    const size_t pbase = (size_t)plane * N * N + c0;

    if (tid < H) {
        float ang = (6.283185307179586f / N) * tid;
        float s, c; sincosf(ang, &s, &c);
        W[tid] = make_float2(c, sgn * s);
    }
    #pragma unroll
    for (int e = 0; e < ELD; e++) {
        int q = tid + e * 256;
        int r = q / TC, cc = q % TC;
        bufA[r][cc] = in[pbase + (size_t)r * N + cc];
    }
    __syncthreads();
    float2 (*X)[TC + 1] = bufA;
    float2 (*Y)[TC + 1] = bufB;
    int m = 1;
    #pragma unroll
    for (int l = H; l >= 1; l >>= 1) {
        #pragma unroll
        for (int e = 0; e < EBF; e++) {
            int idx = tid + e * 256;
            int cc = idx % TC, b = idx / TC;
            int jm = b & ~(m - 1);
            float2 z0 = X[b][cc];
            float2 z1 = X[b + H][cc];
            float2 w  = W[jm];
            float2 s0 = make_float2(z0.x + z1.x, z0.y + z1.y);
            float2 d  = make_float2(z0.x - z1.x, z0.y - z1.y);
            float2 t  = make_float2(d.x * w.x - d.y * w.y, d.x * w.y + d.y * w.x);
            Y[b + jm][cc]     = s0;
            Y[b + jm + m][cc] = t;
        }
        __syncthreads();
        float2 (*tmp)[TC + 1] = X; X = Y; Y = tmp;
        m <<= 1;
    }
    #pragma unroll
    for (int e = 0; e < ELD; e++) {
        int q = tid + e * 256;
        int r = q / TC, cc = q % TC;
        float2 v = X[r][cc];
        if (ABSOUT) {
            outr[pbase + (size_t)r * N + cc] = scale * sqrtf(v.x * v.x + v.y * v.y);
        } else {
            outc[pbase + (size_t)r * N + cc] = make_float2(v.x * scale, v.y * scale);
        }
    }
}

__global__ __launch_bounds__(256)
void extract_feat(const float2* __restrict__ Fc, float* __restrict__ fA,
                  float* __restrict__ fP, int n)
{
    int t = blockIdx.x * 256 + threadIdx.x;
    if (t >= n) return;
    float2 v = Fc[t];
    fA[t] = sqrtf(v.x * v.x + v.y * v.y);
    fP[t] = atan2f(v.y, v.x);
}

// guide extraction, LDS-transposed: E [128 c][65536 n] -> Ga bf16 [n][128],
// Gpf f32 [n][128]. Tile: 128 c x 16 n.
__global__ __launch_bounds__(256)
void gbuild_t(const float2* __restrict__ E, short* __restrict__ Ga,
              float* __restrict__ Gpf)
{
    __shared__ float2 T[128][17];
    const int tid = threadIdx.x;
    const int n0 = blockIdx.x * 16;
    #pragma unroll
    for (int e = 0; e < 8; e++) {
        int q = tid + e * 256;
        int c = q >> 4, nn = q & 15;
        T[c][nn] = E[(size_t)c * 65536 + n0 + nn];
    }
    __syncthreads();
    #pragma unroll
    for (int e = 0; e < 8; e++) {
        int q = tid + e * 256;
        int nn = q >> 7, c = q & 127;
        float2 v = T[c][nn];
        size_t o = (size_t)(n0 + nn) * 128 + c;
        Ga[o]  = f2bf(sqrtf(v.x * v.x + v.y * v.y));
        Gpf[o] = atan2f(v.y, v.x);
    }
}

// mag-path per-shift feat rows: Af bf16 [65536][160] (128 feat + 2 rel + pad)
__global__ __launch_bounds__(256)
void bfeat_a(const float* __restrict__ featA, short* __restrict__ Af, int vx, int vy)
{
    int t = blockIdx.x * 256 + threadIdx.x;
    int n = t / 160, j = t - n * 160;
    int i = n >> 8, jx = n & 255;
    int iy = (2 * i + (vx < 0 ? -3 : 5)) >> 3;
    int ix = (2 * jx + (vy < 0 ? -3 : 5)) >> 3;
    bool valid = (iy >= 0 && iy < 64 && ix >= 0 && ix < 64);
    float v = 0.f;
    if (j < 128)       v = valid ? featA[j * 4096 + iy * 64 + ix] : 0.f;
    else if (j == 128) v = valid ? (0.5f * i - 2.f * iy - 0.75f) : (0.5f * i - 63.75f);
    else if (j == 129) v = valid ? (0.5f * jx - 2.f * ix - 0.75f) : (0.5f * jx - 63.75f);
    Af[(size_t)n * 160 + j] = f2bf(v);
}

// phase-path flat input builder: XpHi/XpLo flat [288*65536] bf16.
// flat[f] = inp[f/258][f%258] for f < 258*65536; 0 for pad rows (258..287).
// The [j][p] view of this SAME flat buffer IS the torch .view scramble.
__global__ __launch_bounds__(256)
void bphase_flat(const float* __restrict__ featP, const float* __restrict__ Gpf,
                 short* __restrict__ XpHi, short* __restrict__ XpLo,
                 int vx, int vy)
{
    unsigned t = blockIdx.x * 256 + threadIdx.x;
    if (t >= 288u * 65536u) return;
    float v = 0.f;
    if (t < 258u * 65536u) {
        unsigned n = t / 258u;
        unsigned c = t - n * 258u;
        int i = (int)(n >> 8), jx = (int)(n & 255);
        int iy = (2 * i + (vx < 0 ? -3 : 5)) >> 3;
        int ix = (2 * jx + (vy < 0 ? -3 : 5)) >> 3;
        bool valid = (iy >= 0 && iy < 64 && ix >= 0 && ix < 64);
        if (c < 128u)       v = valid ? featP[c * 4096 + iy * 64 + ix] : 0.f;
        else if (c < 256u)  v = Gpf[(size_t)n * 128 + (c - 128)];
        else if (c == 256u) v = valid ? (0.5f * i - 2.f * iy - 0.75f) : (0.5f * i - 63.75f);
        else                v = valid ? (0.5f * jx - 2.f * ix - 0.75f) : (0.5f * jx - 63.75f);
    }
    short hi = f2bf(v);
    XpHi[t] = hi;
    XpLo[t] = f2bf(v - bf2f(hi));
}

// ---------------- weight prep ----------------
__global__ void wprep_T(const float* __restrict__ src, short* __restrict__ dst,
                        int Ncols, int Nd, int Kp, int k0, int kn, int kr0, int krn)
{
    int t = blockIdx.x * 256 + threadIdx.x;
    if (t >= Nd * Kp) return;
    int o = t / Kp, j = t - o * Kp;
    int c = (j < kn) ? (k0 + j) : ((j < kn + krn) ? (kr0 + j - kn) : -1);
    float v = 0.f;
    if (c >= 0 && o < Ncols) v = src[(size_t)c * Ncols + o];
    dst[t] = f2bf(v);
}
__global__ void wprep_hilo(const float* __restrict__ src, short* __restrict__ dst,
                           int Nsrc, int Ksrc, int Nd, int Kh, int kn)
{
    int t = blockIdx.x * 256 + threadIdx.x;
    if (t >= Nd * Kh) return;
    int o = t / Kh, j = t - o * Kh;
    float v = 0.f;
    if (j < kn && o < Nsrc) v = src[(size_t)o * Ksrc + j];
    short hi = f2bf(v);
    dst[(size_t)o * (2 * Kh) + j]      = hi;
    dst[(size_t)o * (2 * Kh) + Kh + j] = f2bf(v - bf2f(hi));
}

// ---------------- MFMA GEMM: C[M,*] = act(A[M,K] @ Bt[N,K]^T (+bias)(+Cin))
// ATRANS: A stored k-row-major [K][65536] (flat view); stage via LDS transpose.
//         hi source = A, lo source = Alo (separate flat arrays).
// else  : A row-major [M][Apitch]; HILO lo at col K+k.
template<int HILO, int RELU, int BIAS, int CIN, int OUTF32, int ATRANS = 0>
__global__ __launch_bounds__(256)
void gemm_mfma(const short* __restrict__ A, const short* __restrict__ Alo,
               const short* __restrict__ Bt,
               const float* __restrict__ bias, const void* __restrict__ Cin,
               void* __restrict__ Cout,
               int K, int Apitch, int Bpitch, int ldc, int Nout)
{
    constexpr int NB = HILO ? 2 : 1;
    __shared__ short As[NB * 4096];
    __shared__ short Bs[NB * 4096];
    const int tid = threadIdx.x;
    const int wave = tid >> 6, lane = tid & 63;
    const int bm = blockIdx.y * 128, bn = blockIdx.x * 128;
    const int wr = wave >> 1, wc = wave & 1;
    const int srow = wave * 32 + (lane >> 2);
    const int scol = (lane & 3) * 8;
    const int ldsoff = srow * 32 + scol;
    f32x4 acc[4][4] = {};
    const int ks_n = K >> 5;
    for (int ks = 0; ks < ks_n; ks++) {
        const int k0 = ks << 5;
        if constexpr (ATRANS) {
            // stage A[p][k] from k-row-major flat source, transposed in LDS
            #pragma unroll
            for (int e = 0; e < 2; e++) {
                int q = tid + e * 256;            // 0..511
                int kk = q >> 4, n8 = q & 15;     // k-row, p-octet
                bf16x8 v = *(const bf16x8*)(A + (size_t)(k0 + kk) * Apitch + bm + n8 * 8);
                #pragma unroll
                for (int i = 0; i < 8; i++) As[(n8 * 8 + i) * 32 + kk] = v[i];
                if constexpr (HILO) {
                    bf16x8 v2 = *(const bf16x8*)(Alo + (size_t)(k0 + kk) * Apitch + bm + n8 * 8);
                    #pragma unroll
                    for (int i = 0; i < 8; i++) As[4096 + (n8 * 8 + i) * 32 + kk] = v2[i];
                }
            }
        } else {
            const short* gA = A + (size_t)(bm + srow) * Apitch + k0 + scol;
            gload16(gA, &As[ldsoff]);
            gload16(gA + 16 * Apitch, &As[ldsoff + 512]);
            if constexpr (HILO) {
                const short* gAl = gA + K;
                gload16(gAl, &As[4096 + ldsoff]);
                gload16(gAl + 16 * Apitch, &As[4096 + ldsoff + 512]);
            }
        }
        const short* gB = Bt + (size_t)(bn + srow) * Bpitch + k0 + scol;
        gload16(gB, &Bs[ldsoff]);
        gload16(gB + 16 * Bpitch, &Bs[ldsoff + 512]);
        if constexpr (HILO) {
            const short* gBl = gB + K;
            gload16(gBl, &Bs[4096 + ldsoff]);
            gload16(gBl + 16 * Bpitch, &Bs[4096 + ldsoff + 512]);
        }
        __syncthreads();
        const int fr = lane & 15;
        const int kreg = (lane >> 4) << 3;
        bf16x8 ah[4], bh[4];
        #pragma unroll
        for (int m = 0; m < 4; m++)
            ah[m] = *(const bf16x8*)&As[(wr * 64 + m * 16 + fr) * 32 + kreg];
        #pragma unroll
        for (int n = 0; n < 4; n++)
            bh[n] = *(const bf16x8*)&Bs[(wc * 64 + n * 16 + fr) * 32 + kreg];
        if constexpr (HILO) {
            bf16x8 al[4], bl[4];
            #pragma unroll
            for (int m = 0; m < 4; m++)
                al[m] = *(const bf16x8*)&As[4096 + (wr * 64 + m * 16 + fr) * 32 + kreg];
            #pragma unroll
            for (int n = 0; n < 4; n++)
                bl[n] = *(const bf16x8*)&Bs[4096 + (wc * 64 + n * 16 + fr) * 32 + kreg];
            #pragma unroll
            for (int m = 0; m < 4; m++)
                #pragma unroll
                for (int n = 0; n < 4; n++) {
                    acc[m][n] = __builtin_amdgcn_mfma_f32_16x16x32_bf16(ah[m], bh[n], acc[m][n], 0, 0, 0);
                    acc[m][n] = __builtin_amdgcn_mfma_f32_16x16x32_bf16(al[m], bh[n], acc[m][n], 0, 0, 0);
                    acc[m][n] = __builtin_amdgcn_mfma_f32_16x16x32_bf16(ah[m], bl[n], acc[m][n], 0, 0, 0);
                }
        } else {
            #pragma unroll
            for (int m = 0; m < 4; m++)
                #pragma unroll
                for (int n = 0; n < 4; n++)
                    acc[m][n] = __builtin_amdgcn_mfma_f32_16x16x32_bf16(ah[m], bh[n], acc[m][n], 0, 0, 0);
        }
        __syncthreads();
    }
    const int fr = lane & 15;
    const int rg = (lane >> 4) * 4;
    #pragma unroll
    for (int n = 0; n < 4; n++) {
        const int col = bn + wc * 64 + n * 16 + fr;
        if (col >= Nout) continue;
        const float bv = BIAS ? bias[col] : 0.f;
        #pragma unroll
        for (int m = 0; m < 4; m++) {
            const int row0 = bm + wr * 64 + m * 16 + rg;
            #pragma unroll
            for (int r = 0; r < 4; r++) {
                float v = acc[m][n][r] + bv;
                const size_t ci = (size_t)(row0 + r) * ldc + col;
                if (CIN == 1) v += bf2f(((const short*)Cin)[ci]);
                if (RELU) v = fmaxf(v, 0.f);
                if (OUTF32) ((float*)Cout)[ci] = v;
                else        ((short*)Cout)[ci] = f2bf(v);
            }
        }
    }
}

// depthwise 3x3, channel-last [65536][C] f32 in -> bf16 hi/lo out [65536][2C]
template<int C, int RELU>
__global__ __launch_bounds__(256)
void dwconv_hilo(const float* __restrict__ in, const float* __restrict__ w,
                 short* __restrict__ out)
{
    constexpr int PPB = 256 / C;
    const int tid = threadIdx.x;
    const int c = tid % C, pl = tid / C;
    const int p = blockIdx.x * PPB + pl;
    const int y = p >> 8, x = p & 255;
    float wk[9];
    #pragma unroll
    for (int k = 0; k < 9; k++) wk[k] = w[c * 9 + k];
    float acc = 0.f;
    #pragma unroll
    for (int dy = 0; dy < 3; dy++) {
        int yy = y + dy - 1;
        if (yy < 0 || yy > 255) continue;
        #pragma unroll
        for (int dx = 0; dx < 3; dx++) {
            int xx = x + dx - 1;
            if (xx < 0 || xx > 255) continue;
            acc += in[(size_t)(yy * 256 + xx) * C + c] * wk[dy * 3 + dx];
        }
    }
    if (RELU) acc = fmaxf(acc, 0.f);
    short hi = f2bf(acc);
    out[(size_t)p * (2 * C) + c]     = hi;
    out[(size_t)p * (2 * C) + C + c] = f2bf(acc - bf2f(hi));
}

// dw3: in C3 f32 [65536][33], w [33][9], out f32 [65536][33]
__global__ __launch_bounds__(256)
void dwconv3_f32(const float* __restrict__ in, const float* __restrict__ w,
                 float* __restrict__ out)
{
    const int tid = threadIdx.x;
    const int c = tid & 63, pl = tid >> 6;
    if (c >= 33) return;
    const int p = blockIdx.x * 4 + pl;
    const int y = p >> 8, x = p & 255;
    float wk[9];
    #pragma unroll
    for (int k = 0; k < 9; k++) wk[k] = w[c * 9 + k];
    float acc = 0.f;
    #pragma unroll
    for (int dy = 0; dy < 3; dy++) {
        int yy = y + dy - 1;
        if (yy < 0 || yy > 255) continue;
        #pragma unroll
        for (int dx = 0; dx < 3; dx++) {
            int xx = x + dx - 1;
            if (xx < 0 || xx > 255) continue;
            acc += in[(size_t)(yy * 256 + xx) * 33 + c] * wk[dy * 3 + dx];
        }
    }
    out[(size_t)p * 33 + c] = acc;
}

// ---------------- ensembles ----------------
__global__ __launch_bounds__(256)
void ensemble_a(const short* __restrict__ P, float* __restrict__ mag)
{
    int n = blockIdx.x * 256 + threadIdx.x;
    float w[4]; float mx = -1e30f;
    #pragma unroll
    for (int s = 0; s < 4; s++) {
        w[s] = bf2f(P[((size_t)s * 65536 + n) * 33 + 32]);
        mx = fmaxf(mx, w[s]);
    }
    float sum = 0.f;
    #pragma unroll
    for (int s = 0; s < 4; s++) { w[s] = expf(w[s] - mx); sum += w[s]; }
    float inv = 1.f / sum;
    for (int ch = 0; ch < 32; ch++) {
        float a = 0.f;
        #pragma unroll
        for (int s = 0; s < 4; s++)
            a += bf2f(P[((size_t)s * 65536 + n) * 33 + ch]) * w[s];
        mag[(size_t)ch * 65536 + n] = a * inv;
    }
}

// preds channel-last [65536][33] per shift; output view scramble:
// preds(n,jj) = conv[ch=(n*33+jj)>>16][p=(n*33+jj)&65535] = P[p*33+ch]
__global__ __launch_bounds__(256)
void ensemble_p(const float* __restrict__ P, float* __restrict__ pha)
{
    const size_t SOFF = (size_t)65536 * 33;
    int n = blockIdx.x * 256 + threadIdx.x;
    size_t fw = (size_t)n * 33 + 32;
    int cw = (int)(fw >> 16), pw_ = (int)(fw & 65535);
    float w[4]; float mx = -1e30f;
    #pragma unroll
    for (int s = 0; s < 4; s++) {
        w[s] = P[(size_t)s * SOFF + (size_t)pw_ * 33 + cw];
        mx = fmaxf(mx, w[s]);
    }
    float sum = 0.f;
    #pragma unroll
    for (int s = 0; s < 4; s++) { w[s] = expf(w[s] - mx); sum += w[s]; }
    float inv = 1.f / sum;
    for (int jj = 0; jj < 32; jj++) {
        size_t f = (size_t)n * 33 + jj;
        int c2 = (int)(f >> 16), p2 = (int)(f & 65535);
        float a = 0.f;
        #pragma unroll
        for (int s = 0; s < 4; s++)
            a += P[(size_t)s * SOFF + (size_t)p2 * 33 + c2] * w[s];
        pha[(size_t)jj * 65536 + n] = a * inv;
    }
}

__global__ __launch_bounds__(256)
void make_ffted(const float* __restrict__ mag, const float* __restrict__ pha,
                float2* __restrict__ out)
{
    int t = blockIdx.x * 256 + threadIdx.x;
    float m = mag[t], p = pha[t];
    float s, c; sincosf(p, &s, &c);
    out[t] = make_float2(m * c, m * s);
}

extern "C" void kernel_launch(void* const* d_in, const int* in_sizes, int n_in,
                              void* d_out, int out_size, void* d_ws, size_t ws_size,
                              hipStream_t stream)
{
    (void)in_sizes; (void)n_in; (void)out_size; (void)ws_size;
    const float* feat = (const float*)d_in[0];
    const float* hr   = (const float*)d_in[2];
    const float* w1a  = (const float*)d_in[3];
    const float* b1a  = (const float*)d_in[4];
    const float* w2a  = (const float*)d_in[5];
    const float* b2a  = (const float*)d_in[6];
    const float* w3a  = (const float*)d_in[7];
    const float* b3a  = (const float*)d_in[8];
    const float* pw1  = (const float*)d_in[9];
    const float* dw1  = (const float*)d_in[10];
    const float* dw2  = (const float*)d_in[12];
    const float* pw2  = (const float*)d_in[11];
    const float* pw3  = (const float*)d_in[13];
    const float* dw3  = (const float*)d_in[14];

    // Workspace: 224,133,120 B total (< 257.4 MB proven).
    char* W = (char*)d_ws;
    const size_t oA = 0;                   // 75,497,472: E / XpHi+XpLo / X2 / Af+h1 / C3 / Hp
    const size_t oB = 75497472;            // 67,108,864: Fc / Ga+H1g+h2 / C1 / C2+X3 / Z
    const size_t oC = oB + 67108864;       // 33,554,432: Gpf f32 [65536][128]
    const size_t oD = oC + 33554432;       // 34,603,008: PA bf16 / PP f32 [4][65536][33]
    const size_t oM = oD + 34603008;       // 12,582,912: featA, featP, Hm
    const size_t oF = oM + 12582912;       //    786,432: weights

    float2* E    = (float2*)(W + oA);
    short*  XpHi = (short*) (W + oA);
    short*  XpLo = (short*) (W + oA + 37748736);
    short*  X2   = (short*) (W + oA);
    short*  Af   = (short*) (W + oA);
    short*  h1   = (short*) (W + oA + 20971520);
    float*  C3   = (float*) (W + oA);
    float*  Hp   = (float*) (W + oA);
    float2* Fc   = (float2*)(W + oB);
    short*  Ga   = (short*) (W + oB);
    short*  H1g  = (short*) (W + oB + 16777216);
    short*  h2   = (short*) (W + oB + 50331648);
    float*  C1   = (float*) (W + oB);
    float*  C2   = (float*) (W + oB);
    short*  X3   = (short*) (W + oB + 33554432);
    float2* Z    = (float2*)(W + oB);
    float*  Gpf  = (float*) (W + oC);
    short*  PA   = (short*) (W + oD);
    float*  PP   = (float*) (W + oD);
    float*  featA = (float*)(W + oM);
    float*  featP = (float*)(W + oM + 2097152);
    float*  Hm    = (float*)(W + oM + 4194304);
    short* W1f = (short*)(W + oF);             //  81,920 B [256][160]
    short* W1g = (short*)(W + oF + 81920);     //  65,536 B [256][128]
    short* W2  = (short*)(W + oF + 147456);    //  65,536 B [128][256]
    short* W3  = (short*)(W + oF + 212992);    //  32,768 B [128][128]
    short* Pf  = (short*)(W + oF + 245760);    // 294,912 B [256][576]
    short* P2  = (short*)(W + oF + 540672);    // 131,072 B [128][512]
    short* P3  = (short*)(W + oF + 671744);    //  65,536 B [128][256]

    // ---- weight prep ----
    wprep_T<<<160, 256, 0, stream>>>(w1a, W1f, 256, 256, 160, 0, 128, 256, 2);
    wprep_T<<<128, 256, 0, stream>>>(w1a, W1g, 256, 256, 128, 128, 128, 0, 0);
    wprep_T<<<128, 256, 0, stream>>>(w2a, W2, 128, 128, 256, 0, 256, 0, 0);
    wprep_T<<<64,  256, 0, stream>>>(w3a, W3, 33, 128, 128, 0, 128, 0, 0);
    wprep_hilo<<<288, 256, 0, stream>>>(pw1, Pf, 256, 258, 256, 288, 258);
    wprep_hilo<<<128, 256, 0, stream>>>(pw2, P2, 128, 256, 128, 256, 256);
    wprep_hilo<<<64,  256, 0, stream>>>(pw3, P3, 33, 128, 128, 128, 128);

    // ---- forward FFTs: rows via fft_lines (coalesced), cols via fft_cols --
    fft_lines<256, true ><<<16384, 256, 0, stream>>>(hr, nullptr, E, 32768, 256, 65536, 256, 1, -1.f, 1.f);
    fft_cols<256, 8, 0><<<dim3(32, 128), 256, 0, stream>>>(E, E, nullptr, -1.f, 1.f);
    fft_lines<64,  true ><<<1024,  256, 0, stream>>>(feat, nullptr, Fc, 8192, 64, 4096, 64, 1, -1.f, 1.f);
    fft_cols<64, 8, 0><<<dim3(8, 128), 256, 0, stream>>>(Fc, Fc, nullptr, -1.f, 1.f);
    extract_feat<<<2048, 256, 0, stream>>>(Fc, featA, featP, 524288);

    // ---- guide mags/angles, LDS-transposed (E dead after) ----
    gbuild_t<<<4096, 256, 0, stream>>>(E, Ga, Gpf);

    // ---- mag-path guide contribution (shift-independent) ----
    gemm_mfma<0,0,0,0,0><<<dim3(2,512), 256, 0, stream>>>(Ga, nullptr, W1g, nullptr, nullptr, H1g, 128, 128, 128, 256, 256);

    // ---- magnitude path ----
    for (int s = 0; s < 4; s++) {
        int vx = (s < 2) ? -1 : 1;
        int vy = (s & 1) ? 1 : -1;
        bfeat_a<<<40960, 256, 0, stream>>>(featA, Af, vx, vy);
        gemm_mfma<0,1,1,1,0><<<dim3(2,512), 256, 0, stream>>>(Af, nullptr, W1f, b1a, H1g, h1, 160, 160, 160, 256, 256);
        gemm_mfma<0,1,1,0,0><<<dim3(1,512), 256, 0, stream>>>(h1, nullptr, W2, b2a, nullptr, h2, 256, 256, 256, 128, 128);
        gemm_mfma<0,0,1,0,0><<<dim3(1,512), 256, 0, stream>>>(h2, nullptr, W3, b3a, nullptr, PA + (size_t)s * 65536 * 33, 128, 128, 128, 33, 33);
    }
    ensemble_a<<<256, 256, 0, stream>>>(PA, Hm);

    // ---- phase path: flat input + ATRANS GEMM (scramble = flat view) ----
    for (int s = 0; s < 4; s++) {
        int vx = (s < 2) ? -1 : 1;
        int vy = (s & 1) ? 1 : -1;
        bphase_flat<<<73728, 256, 0, stream>>>(featP, Gpf, XpHi, XpLo, vx, vy);
        gemm_mfma<1,0,0,0,1,1><<<dim3(2,512), 256, 0, stream>>>(XpHi, XpLo, Pf, nullptr, nullptr, C1, 288, 65536, 576, 256, 256);
        dwconv_hilo<256,1><<<65536, 256, 0, stream>>>(C1, dw1, X2);
        gemm_mfma<1,0,0,0,1><<<dim3(1,512), 256, 0, stream>>>(X2, nullptr, P2, nullptr, nullptr, C2, 256, 512, 512, 128, 128);
        dwconv_hilo<128,1><<<32768, 256, 0, stream>>>(C2, dw2, X3);
        gemm_mfma<1,0,0,0,1><<<dim3(1,512), 256, 0, stream>>>(X3, nullptr, P3, nullptr, nullptr, C3, 128, 256, 256, 33, 33);
        dwconv3_f32<<<16384, 256, 0, stream>>>(C3, dw3, PP + (size_t)s * 65536 * 33);
    }
    ensemble_p<<<256, 256, 0, stream>>>(PP, Hp);

    // ---- recombine + inverse FFT (col pass fuses final |.|) ----
    make_ffted<<<8192, 256, 0, stream>>>(Hm, Hp, Z);
    fft_lines<256, false><<<4096, 256, 0, stream>>>(nullptr, Z, Z, 8192, 256, 65536, 256, 1, 1.f, 1.f / 256.f);
    fft_cols<256, 8, 1><<<dim3(32, 32), 256, 0, stream>>>(Z, nullptr, (float*)d_out, 1.f, 1.f / 256.f);
}